// Round 7
// baseline (96.933 us; speedup 1.0000x reference)
//
#include <hip/hip_runtime.h>
#include <hip/hip_cooperative_groups.h>

namespace cg = cooperative_groups;

#define NBINS  256
#define BATCH  4
#define NPIX   65536     // H*W per batch, C == 1
#define EPSF   1e-10f
#define RSTRIP 16        // joint rows owned per block (phase A)
#define NSTRIP 16        // NBINS / RSTRIP
#define NQ     4         // scan quarters
#define QPIX   (NPIX / NQ)

// ---------------------------------------------------------------------------
// Single cooperative kernel, 256 blocks x 1024 threads (1 block/CU).
// Phase A: block (b,s,q) scans quarter q of batch b into a 16x256 LDS strip
//   (2-tap Gaussian: sigma=0.1, spacing 1.0 -> 3rd bin ~ exp(-50), negligible)
//   and flushes quarter-partials with plain stores. Marginals: (s,q) owns the
//   l>>8==s slice of its quarter (each pixel counted exactly once).
// grid.sync()
// Phase B: block (g=b*16+s, colgroup) merges the 4 quarter strips for a
//   16-row x 64-col tile (1 cell/thread) and reduces S=sum(c), T=sum(c*log2c)
//   (both LINEAR in c -> no normalization pass). cg==0 blocks merge marginals.
// grid.sync()
// Phase C: block 0 reduces S/T per batch, merges marginals, computes the
//   entropies with the reference's eps placement, H12 via
//   log2(S+eps)*S/(S+eps) - T/(S+eps)  (~1e-5-bit deviation), stores out.
// No global atomics, no memsets, no cross-call state; fully deterministic.
// Denormal guard (round-5 lesson): cells can hold denormal masses; v_log_f32
// flushes denormal inputs -> -inf -> NaN. Guard at 1e-30 (error < 1e-28).
// ---------------------------------------------------------------------------
__global__ __launch_bounds__(1024) void mi_fused(
    const float* __restrict__ in1, const float* __restrict__ in2,
    float* __restrict__ Jpart,                       // 256 * 4096
    float* __restrict__ M1q, float* __restrict__ M2q,    // 256 * 256 each
    float* __restrict__ M1m, float* __restrict__ M2m,    // 64 * 256 each
    float* __restrict__ STs, float* __restrict__ STt,    // 256 each
    float* __restrict__ out)
{
    __shared__ float js[RSTRIP * NBINS];   // 16 KB
    __shared__ float h1[NBINS];
    __shared__ float h2[NBINS];
    __shared__ float red[1024];
    __shared__ float sb[BATCH], tb[BATCH], nmiS[BATCH];

    const int t   = threadIdx.x;           // 0..1023
    const int blk = blockIdx.x;            // == (b*16+s)*4 + q

    // ========================= Phase A =========================
    {
        const int b  = blk >> 6;
        const int s  = (blk >> 2) & (NSTRIP - 1);
        const int q  = blk & (NQ - 1);
        const int r0 = s << 4;

#pragma unroll
        for (int i = 0; i < 4; ++i) js[(i << 10) + t] = 0.0f;
        if (t < NBINS) { h1[t] = 0.0f; h2[t] = 0.0f; }
        __syncthreads();

        const float4* __restrict__ p1 = (const float4*)(in1 + b * NPIX) + q * (QPIX / 4);
        const float4* __restrict__ p2 = (const float4*)(in2 + b * NPIX) + q * (QPIX / 4);

#pragma unroll
        for (int it = 0; it < QPIX / 4096; ++it) {   // 4 iterations
            const int l = (it << 10) + t;            // float4 idx in quarter
            const float4 a = p1[l];
            const float4 c = p2[l];
            const bool mflag = (l >> 8) == s;        // marginal ownership

            const float vx1[4] = { a.x, a.y, a.z, a.w };
            const float vx2[4] = { c.x, c.y, c.z, c.w };
#pragma unroll
            for (int j = 0; j < 4; ++j) {
                const float v1 = vx1[j] * 255.0f;    // in [0,255)
                const float v2 = vx2[j] * 255.0f;
                const int k1 = (int)v1;              // floor, <= 254
                const int k2 = (int)v2;
                const float d1 = v1 - (float)k1;
                const float d2 = v2 - (float)k2;
                const float e1 = d1 - 1.0f;
                const float e2 = d2 - 1.0f;
                const float w1a = __expf(-50.0f * d1 * d1);
                const float w1b = __expf(-50.0f * e1 * e1);
                const float w2a = __expf(-50.0f * d2 * d2);
                const float w2b = __expf(-50.0f * e2 * e2);

                const int r = k1 - r0;
                if ((unsigned)r < RSTRIP) {
                    atomicAdd(&js[(r << 8) + k2],     w1a * w2a);
                    atomicAdd(&js[(r << 8) + k2 + 1], w1a * w2b);
                }
                if ((unsigned)(r + 1) < RSTRIP) {
                    atomicAdd(&js[((r + 1) << 8) + k2],     w1b * w2a);
                    atomicAdd(&js[((r + 1) << 8) + k2 + 1], w1b * w2b);
                }
                if (mflag) {
                    atomicAdd(&h1[k1],     w1a);
                    atomicAdd(&h1[k1 + 1], w1b);
                    atomicAdd(&h2[k2],     w2a);
                    atomicAdd(&h2[k2 + 1], w2b);
                }
            }
        }
        __syncthreads();

        float* __restrict__ Jq = Jpart + ((size_t)blk << 12);
#pragma unroll
        for (int i = 0; i < 4; ++i) { const int idx = (i << 10) + t; Jq[idx] = js[idx]; }
        if (t < NBINS) {
            M1q[(blk << 8) + t] = h1[t];
            M2q[(blk << 8) + t] = h2[t];
        }
    }

    cg::this_grid().sync();

    // ========================= Phase B =========================
    {
        const int g    = blk >> 2;                   // b*16+s, 0..63
        const int cgrp = blk & 3;                    // 64-col group
        const int ri   = t >> 6;                     // row in strip 0..15
        const int col  = (cgrp << 6) + (t & 63);
        const size_t ci = ((size_t)ri << 8) + col;
        const float* __restrict__ J0 = Jpart + ((size_t)(g << 2) << 12);

        const float c = J0[ci] + J0[ci + 4096] + J0[ci + 8192] + J0[ci + 12288];
        float S = c;
        float T = (c > 1e-30f) ? c * __log2f(c) : 0.0f;
#pragma unroll
        for (int m = 32; m >= 1; m >>= 1) { S += __shfl_xor(S, m); T += __shfl_xor(T, m); }
        const int wid = t >> 6, lane = t & 63;
        if (lane == 0) { red[wid] = S; red[32 + wid] = T; }

        // marginal merge: cg==0 blocks, threads 0..511
        if (cgrp == 0 && t < 512) {
            const int arr = t >> 8, bin = t & 255;
            const float* __restrict__ Mq = (arr == 0 ? M1q : M2q) + (g << 10) + bin;
            const float mv = Mq[0] + Mq[256] + Mq[512] + Mq[768];
            if (arr == 0) M1m[(g << 8) + bin] = mv;
            else          M2m[(g << 8) + bin] = mv;
        }
        __syncthreads();
        if (t == 0) {
            float ss = 0.0f, tt = 0.0f;
#pragma unroll
            for (int w = 0; w < 16; ++w) { ss += red[w]; tt += red[32 + w]; }
            STs[blk] = ss; STt[blk] = tt;
        }
    }

    cg::this_grid().sync();

    // ========================= Phase C (block 0) =========================
    if (blk == 0) {
        const int wid = t >> 6, lane = t & 63;
        if (wid < BATCH) {                           // batch b = wave id
            float S = STs[(wid << 6) + lane];        // 64 ST entries per batch
            float T = STt[(wid << 6) + lane];
#pragma unroll
            for (int m = 32; m >= 1; m >>= 1) { S += __shfl_xor(S, m); T += __shfl_xor(T, m); }
            if (lane == 0) { sb[wid] = S; tb[wid] = T; }
        }
        __syncthreads();

        const int b = t >> 8, bin = t & 255;
        const float invN = 1.0f / (float)NPIX;
        const float* __restrict__ q1 = M1m + ((size_t)b << 12) + bin;  // b*16*256
        const float* __restrict__ q2 = M2m + ((size_t)b << 12) + bin;
        float a1 = 0.0f, a2 = 0.0f;
#pragma unroll
        for (int s = 0; s < 16; ++s) { a1 += q1[s << 8]; a2 += q2[s << 8]; }
        const float pre1 = a1 * invN, pre2 = a2 * invN;

        auto segreduce = [&](float v) -> float {     // per-256 segment sum
            red[t] = v; __syncthreads();
            for (int s = 128; s > 0; s >>= 1) {
                if (bin < s) red[t] += red[t + s];
                __syncthreads();
            }
            const float r = red[b << 8];
            __syncthreads();
            return r;
        };

        const float sum1 = segreduce(pre1);
        const float p1 = pre1 / (sum1 + EPSF);
        const float H1 = segreduce(-p1 * __log2f(p1 + EPSF));

        const float sum2 = segreduce(pre2);
        const float p2 = pre2 / (sum2 + EPSF);
        const float H2 = segreduce(-p2 * __log2f(p2 + EPSF));

        if (bin == 0) {
            const float Sp  = sb[b] + EPSF;
            const float H12 = __log2f(Sp) * (sb[b] / Sp) - tb[b] / Sp;
            const float mi  = H1 + H2 - H12;
            nmiS[b] = 2.0f * mi / (H1 + H2);
        }
        __syncthreads();
        if (t == 0) *out = 0.25f * (nmiS[0] + nmiS[1] + nmiS[2] + nmiS[3]);
    }
}

// ---------------------------------------------------------------------------
extern "C" void kernel_launch(void* const* d_in, const int* in_sizes, int n_in,
                              void* d_out, int out_size, void* d_ws, size_t ws_size,
                              hipStream_t stream)
{
    const float* in1 = (const float*)d_in[0];
    const float* in2 = (const float*)d_in[1];

    float* Jpart = (float*)d_ws;                      // 256*4096 = 1,048,576
    float* M1q   = Jpart + (size_t)256 * 4096;        // 65,536
    float* M2q   = M1q + 65536;                       // 65,536
    float* M1m   = M2q + 65536;                       // 16,384
    float* M2m   = M1m + 16384;                       // 16,384
    float* STs   = M2m + 16384;                       // 256
    float* STt   = STs + 256;                         // 256
    float* outp  = (float*)d_out;

    void* args[] = { (void*)&in1, (void*)&in2, (void*)&Jpart, (void*)&M1q, (void*)&M2q,
                     (void*)&M1m, (void*)&M2m, (void*)&STs, (void*)&STt, (void*)&outp };
    (void)hipLaunchCooperativeKernel((const void*)mi_fused, dim3(256), dim3(1024),
                                     args, 0, stream);
}

// Round 9
// 41.440 us; speedup vs baseline: 2.3391x; 2.3391x over previous
//
#include <hip/hip_runtime.h>

#define NBINS   256
#define BATCH   4
#define NPIX    65536        // H*W per batch, C == 1
#define EPSF    1e-10f
#define RSTRIP  32           // joint rows owned per block
#define NSTRIP  8            // strips per batch
#define NSLICE  8            // pixel slices per batch (NSTRIP*NSLICE = 64 blocks/batch)
#define SLICEPIX (NPIX / NSLICE)       // 8192 pixels

// ---------------------------------------------------------------------------
// Node 1: block (b, s, q) scans slice q of batch b, accumulating rows
// [32s, 32s+32) of the joint histogram in a 32 KB LDS strip, flushed with
// plain stores to Jpart[blk] (no global atomics, no memsets). 2-tap Gaussian
// (sigma=0.1, spacing 1.0 -> 3rd bin ~ exp(-50), < 1e-16 relative).
// Marginals: within slice q, the wave-group (it*4 + t>>8) == s owns 1024
// pixels -> each pixel counted exactly once; partials stored to M1/M2part.
// Block 0 resets the phase-2 ticket (poison/replay-safe).
// ---------------------------------------------------------------------------
__global__ __launch_bounds__(1024) void mi_strip(
    const float* __restrict__ in1, const float* __restrict__ in2,
    float* __restrict__ Jpart, float* __restrict__ M1part,
    float* __restrict__ M2part, unsigned* __restrict__ ticket)
{
    __shared__ float js[RSTRIP * NBINS];   // 32 KB
    __shared__ float h1[NBINS];
    __shared__ float h2[NBINS];

    const int t   = threadIdx.x;           // 0..1023
    const int blk = blockIdx.x;            // (b*8+s)*8+q
    const int b   = blk >> 6;
    const int s   = (blk >> 3) & (NSTRIP - 1);
    const int q   = blk & (NSLICE - 1);
    const int r0  = s << 5;

    if (blk == 0 && t == 0) *ticket = 0u;  // reset for the entrop kernel

#pragma unroll
    for (int i = 0; i < 8; ++i) js[(i << 10) + t] = 0.0f;
    if (t < NBINS) { h1[t] = 0.0f; h2[t] = 0.0f; }
    __syncthreads();

    const float4* __restrict__ p1 = (const float4*)(in1 + b * NPIX) + q * (SLICEPIX / 4);
    const float4* __restrict__ p2 = (const float4*)(in2 + b * NPIX) + q * (SLICEPIX / 4);

#pragma unroll
    for (int it = 0; it < 2; ++it) {                 // 2048 float4 per slice
        const int l = (it << 10) + t;
        const float4 a = p1[l];
        const float4 c = p2[l];
        const bool mflag = ((it << 2) + (t >> 8)) == s;   // wave-uniform

        const float vx1[4] = { a.x, a.y, a.z, a.w };
        const float vx2[4] = { c.x, c.y, c.z, c.w };
#pragma unroll
        for (int j = 0; j < 4; ++j) {
            const float v1 = vx1[j] * 255.0f;        // in [0,255)
            const float v2 = vx2[j] * 255.0f;
            const int k1 = (int)v1;                  // floor, <= 254
            const int k2 = (int)v2;
            const float d1 = v1 - (float)k1;
            const float d2 = v2 - (float)k2;
            const float e1 = d1 - 1.0f;
            const float e2 = d2 - 1.0f;
            const float w1a = __expf(-50.0f * d1 * d1);
            const float w1b = __expf(-50.0f * e1 * e1);
            const float w2a = __expf(-50.0f * d2 * d2);
            const float w2b = __expf(-50.0f * e2 * e2);

            const int r = k1 - r0;
            if ((unsigned)r < RSTRIP) {              // row k1 in strip
                atomicAdd(&js[(r << 8) + k2],     w1a * w2a);
                atomicAdd(&js[(r << 8) + k2 + 1], w1a * w2b);
            }
            if ((unsigned)(r + 1) < RSTRIP) {        // row k1+1 in strip
                atomicAdd(&js[((r + 1) << 8) + k2],     w1b * w2a);
                atomicAdd(&js[((r + 1) << 8) + k2 + 1], w1b * w2b);
            }
            if (mflag) {
                atomicAdd(&h1[k1],     w1a);
                atomicAdd(&h1[k1 + 1], w1b);
                atomicAdd(&h2[k2],     w2a);
                atomicAdd(&h2[k2 + 1], w2b);
            }
        }
    }
    __syncthreads();

    float* __restrict__ Jq = Jpart + ((size_t)blk << 13);    // 8192 floats/blk
#pragma unroll
    for (int i = 0; i < 8; ++i) { const int idx = (i << 10) + t; Jq[idx] = js[idx]; }
    if (t < NBINS) {
        M1part[(blk << 8) + t] = h1[t];
        M2part[(blk << 8) + t] = h2[t];
    }
}

// ---------------------------------------------------------------------------
// Node 2: 256 blocks. Block g merges the 8 slice-partials for 4 joint rows
// (1 cell/thread, coalesced) and reduces S = sum(c), T = sum(c*log2 c) --
// both LINEAR in c, so no normalization pass. Denormal guard (round-5
// lesson): v_log_f32 flushes denormal input -> -inf -> NaN; guard at 1e-30
// (discarded |c log2 c| < 1e-28). The LAST block (device ticket, release/
// acquire via __threadfence) reduces STs/STt in fixed order, merges the 64
// marginal partials per bin, reproduces the reference's eps placement for
// H1/H2, reconstructs H12 = log2(S+eps)*S/(S+eps) - T/(S+eps) (~1e-5-bit
// deviation), and plain-stores the mean normalized MI.
// ---------------------------------------------------------------------------
__global__ __launch_bounds__(1024) void mi_entrop(
    const float* __restrict__ Jpart,
    const float* __restrict__ M1part, const float* __restrict__ M2part,
    float* __restrict__ STs, float* __restrict__ STt,
    unsigned* __restrict__ ticket, float* __restrict__ out)
{
    __shared__ float red[1024];
    __shared__ float sb[BATCH], tb[BATCH], nmiS[BATCH];
    __shared__ unsigned tick;

    const int t = threadIdx.x;
    const int g = blockIdx.x;              // 0..255
    const int b = g >> 6;
    const int rg = g & 63;                 // 4-row group within batch
    const int s  = rg >> 3;                // strip (32 rows)
    const int ri = t >> 8;                 // 0..3
    const int col = t & (NBINS - 1);
    const int lr = (rg << 2) + ri - (s << 5);        // local row in strip

    const float* __restrict__ J0 = Jpart + ((size_t)(b * NSTRIP + s) << 16);
    const size_t off = ((size_t)lr << 8) + col;

    float c = 0.0f;
#pragma unroll
    for (int q = 0; q < NSLICE; ++q) c += J0[((size_t)q << 13) + off];
    float S = c;
    float T = (c > 1e-30f) ? c * __log2f(c) : 0.0f;
#pragma unroll
    for (int m = 32; m >= 1; m >>= 1) { S += __shfl_xor(S, m); T += __shfl_xor(T, m); }
    const int wid = t >> 6, lane = t & 63;
    if (lane == 0) { red[wid] = S; red[16 + wid] = T; }
    __syncthreads();
    if (t == 0) {
        float ss = 0.0f, tt = 0.0f;
#pragma unroll
        for (int w = 0; w < 16; ++w) { ss += red[w]; tt += red[16 + w]; }
        STs[g] = ss; STt[g] = tt;
        __threadfence();                   // release STs/STt device-wide
        tick = atomicAdd(ticket, 1u);
    }
    __syncthreads();
    if (tick != 255u) return;              // uniform: tick is LDS-shared
    __threadfence();                       // acquire peers' STs/STt

    // ======================= final combine (last block) =======================
    if (wid < BATCH) {                     // batch = wave id; 64 ST entries each
        float Sv = STs[(wid << 6) + lane];
        float Tv = STt[(wid << 6) + lane];
#pragma unroll
        for (int m = 32; m >= 1; m >>= 1) { Sv += __shfl_xor(Sv, m); Tv += __shfl_xor(Tv, m); }
        if (lane == 0) { sb[wid] = Sv; tb[wid] = Tv; }
    }
    __syncthreads();

    const int bb = t >> 8, bin = t & (NBINS - 1);
    const float invN = 1.0f / (float)NPIX;
    const float* __restrict__ q1 = M1part + ((size_t)bb << 14) + bin;  // 64 partials
    const float* __restrict__ q2 = M2part + ((size_t)bb << 14) + bin;
    float a1 = 0.0f, a2 = 0.0f;
#pragma unroll 8
    for (int j = 0; j < 64; ++j) { a1 += q1[(size_t)j << 8]; a2 += q2[(size_t)j << 8]; }
    const float pre1 = a1 * invN, pre2 = a2 * invN;

    auto segreduce = [&](float v) -> float {         // per-256 segment sum
        red[t] = v; __syncthreads();
        for (int st = 128; st > 0; st >>= 1) {
            if (bin < st) red[t] += red[t + st];
            __syncthreads();
        }
        const float r = red[bb << 8];
        __syncthreads();
        return r;
    };

    const float sum1 = segreduce(pre1);
    const float p1 = pre1 / (sum1 + EPSF);
    const float H1 = segreduce(-p1 * __log2f(p1 + EPSF));

    const float sum2 = segreduce(pre2);
    const float p2 = pre2 / (sum2 + EPSF);
    const float H2 = segreduce(-p2 * __log2f(p2 + EPSF));

    if (bin == 0) {
        const float Sp  = sb[bb] + EPSF;
        const float H12 = __log2f(Sp) * (sb[bb] / Sp) - tb[bb] / Sp;
        const float mi  = H1 + H2 - H12;
        nmiS[bb] = 2.0f * mi / (H1 + H2);
    }
    __syncthreads();
    if (t == 0) *out = 0.25f * (nmiS[0] + nmiS[1] + nmiS[2] + nmiS[3]);
}

// ---------------------------------------------------------------------------
extern "C" void kernel_launch(void* const* d_in, const int* in_sizes, int n_in,
                              void* d_out, int out_size, void* d_ws, size_t ws_size,
                              hipStream_t stream)
{
    const float* in1 = (const float*)d_in[0];
    const float* in2 = (const float*)d_in[1];

    float*    Jpart  = (float*)d_ws;                        // 256 * 8192 = 2M floats
    float*    M1part = Jpart + (size_t)256 * 8192;          // 256*256 = 64K
    float*    M2part = M1part + 65536;                      // 64K
    float*    STs    = M2part + 65536;                      // 256
    float*    STt    = STs + 256;                           // 256
    unsigned* ticket = (unsigned*)(STt + 256);              // 1
    float*    outp   = (float*)d_out;

    // All workspace regions fully overwritten each call; ticket reset by
    // mi_strip block 0 -> no memset nodes, 2 kernel nodes total.
    mi_strip<<<256, 1024, 0, stream>>>(in1, in2, Jpart, M1part, M2part, ticket);
    mi_entrop<<<256, 1024, 0, stream>>>(Jpart, M1part, M2part, STs, STt, ticket, outp);
}

// Round 10
// 41.247 us; speedup vs baseline: 2.3501x; 1.0047x over previous
//
#include <hip/hip_runtime.h>

#define NBINS  256
#define BATCH  4
#define NPIX   65536     // H*W per batch, C == 1
#define EPSF   1e-10f
#define RSTRIP 16        // joint rows owned per block
#define NSTRIP 16        // NBINS / RSTRIP
#define NQ     4         // scan quarters
#define QPIX   (NPIX / NQ)

// ---------------------------------------------------------------------------
// Node 1 (= round 6's proven mi_strip): block (b, s, q) scans quarter q of
// batch b into a 16x256 LDS strip (2-tap Gaussian: sigma=0.1, spacing 1.0 ->
// 3rd bin ~ exp(-50), < 1e-16 relative), flushed with plain stores to the
// quarter image Jpart[b][q]. Marginals: (s,q) owns the l>>8==s slice of its
// quarter (each pixel counted exactly once); partials stored to S1/S2part.
// Block 0 also resets the node-2 ticket and (S,T) accumulators
// (poison/replay-safe; visible to node 2 via the kernel boundary).
// ---------------------------------------------------------------------------
__global__ __launch_bounds__(1024) void mi_strip(
    const float* __restrict__ in1, const float* __restrict__ in2,
    float* __restrict__ S1part, float* __restrict__ S2part,
    float* __restrict__ Jpart,
    float* __restrict__ accS, float* __restrict__ accT,
    unsigned* __restrict__ ticket)
{
    __shared__ float js[RSTRIP * NBINS];   // 16 KB
    __shared__ float h1[NBINS];
    __shared__ float h2[NBINS];

    const int t  = threadIdx.x;            // 0..1023
    const int b  = blockIdx.x >> 6;
    const int s  = (blockIdx.x >> 2) & (NSTRIP - 1);
    const int q  = blockIdx.x & (NQ - 1);
    const int r0 = s << 4;

    if (blockIdx.x == 0 && t == 0) {
        *ticket = 0u;
#pragma unroll
        for (int i = 0; i < BATCH; ++i) { accS[i] = 0.0f; accT[i] = 0.0f; }
    }

#pragma unroll
    for (int i = 0; i < 4; ++i) js[(i << 10) + t] = 0.0f;
    if (t < NBINS) { h1[t] = 0.0f; h2[t] = 0.0f; }
    __syncthreads();

    const float4* __restrict__ p1 = (const float4*)(in1 + b * NPIX) + q * (QPIX / 4);
    const float4* __restrict__ p2 = (const float4*)(in2 + b * NPIX) + q * (QPIX / 4);

#pragma unroll
    for (int it = 0; it < QPIX / 4096; ++it) {   // 4 iterations
        const int l = (it << 10) + t;            // float4 idx in quarter
        const float4 a = p1[l];
        const float4 c = p2[l];
        const bool mflag = (l >> 8) == s;        // marginal ownership

        const float vx1[4] = { a.x, a.y, a.z, a.w };
        const float vx2[4] = { c.x, c.y, c.z, c.w };
#pragma unroll
        for (int j = 0; j < 4; ++j) {
            const float v1 = vx1[j] * 255.0f;    // in [0,255)
            const float v2 = vx2[j] * 255.0f;
            const int k1 = (int)v1;              // floor, <= 254
            const int k2 = (int)v2;
            const float d1 = v1 - (float)k1;
            const float d2 = v2 - (float)k2;
            const float e1 = d1 - 1.0f;
            const float e2 = d2 - 1.0f;
            const float w1a = __expf(-50.0f * d1 * d1);
            const float w1b = __expf(-50.0f * e1 * e1);
            const float w2a = __expf(-50.0f * d2 * d2);
            const float w2b = __expf(-50.0f * e2 * e2);

            const int r = k1 - r0;
            if ((unsigned)r < RSTRIP) {
                atomicAdd(&js[(r << 8) + k2],     w1a * w2a);
                atomicAdd(&js[(r << 8) + k2 + 1], w1a * w2b);
            }
            if ((unsigned)(r + 1) < RSTRIP) {
                atomicAdd(&js[((r + 1) << 8) + k2],     w1b * w2a);
                atomicAdd(&js[((r + 1) << 8) + k2 + 1], w1b * w2b);
            }
            if (mflag) {
                atomicAdd(&h1[k1],     w1a);
                atomicAdd(&h1[k1 + 1], w1b);
                atomicAdd(&h2[k2],     w2a);
                atomicAdd(&h2[k2 + 1], w2b);
            }
        }
    }
    __syncthreads();

    // strip rows are contiguous rows [r0, r0+16) of quarter image (b,q)
    float* __restrict__ Jq = Jpart + ((size_t)(b * NQ + q) << 16) + (r0 << 8);
#pragma unroll
    for (int i = 0; i < 4; ++i) { const int idx = (i << 10) + t; Jq[idx] = js[idx]; }
    if (t < NBINS) {
        const size_t po = (size_t)((b * NSTRIP + s) * NQ + q) << 8;
        S1part[po + t] = h1[t];
        S2part[po + t] = h2[t];
    }
}

// ---------------------------------------------------------------------------
// Node 2: 256 blocks, 1 joint cell per thread. Block g=(b,rowgroup) merges
// the 4 quarter partials and reduces S = sum(c), T = sum(c*log2 c) -- both
// LINEAR in c, so no normalization pass (H12 reconstructed as
// log2(S+eps)*S/(S+eps) - T/(S+eps), ~1e-5-bit deviation from the
// reference's eps-inside-log). Denormal guard (round-5 lesson): v_log_f32
// flushes denormal input -> -inf -> NaN; guard at 1e-30 (|c log2 c|<1e-28).
// FENCE-FREE merge (round-9 lesson: __threadfence = cross-XCD L2 writeback,
// expensive): thread 0 atomicAdds (S,T) into per-batch accumulators, and the
// ticket add is ordered AFTER those atomics complete at L2 by consuming the
// returned old values (forces s_waitcnt vmcnt on own atomics only). The
// 256th block reads the accumulators via atomicAdd(p, 0) -- coherent -- and
// runs the marginal/entropy tail (S1/S2part are node-1 plain stores, safe
// across the kernel boundary). FP-atomic order wiggle <= ~1e-4: harmless.
// ---------------------------------------------------------------------------
__global__ __launch_bounds__(1024) void mi_entrop(
    const float* __restrict__ Jpart,
    const float* __restrict__ S1part, const float* __restrict__ S2part,
    float* __restrict__ accS, float* __restrict__ accT,
    unsigned* __restrict__ ticket, float* __restrict__ out)
{
    __shared__ float red[1024];
    __shared__ float sb[BATCH], tb[BATCH], nmiS[BATCH];
    __shared__ unsigned tickS;

    const int t   = threadIdx.x;
    const int g   = blockIdx.x;            // 0..255
    const int b   = g >> 6;
    const int row = ((g & 63) << 2) + (t >> 8);      // 0..255
    const int col = t & (NBINS - 1);
    const size_t off = ((size_t)row << 8) + col;
    const float* __restrict__ J0 = Jpart + ((size_t)(b * NQ) << 16);

    const float c = J0[off] + J0[off + (1 << 16)]
                  + J0[off + (2 << 16)] + J0[off + (3 << 16)];
    float S = c;
    float T = (c > 1e-30f) ? c * __log2f(c) : 0.0f;
#pragma unroll
    for (int m = 32; m >= 1; m >>= 1) { S += __shfl_xor(S, m); T += __shfl_xor(T, m); }
    const int wid = t >> 6, lane = t & 63;
    if (lane == 0) { red[wid] = S; red[16 + wid] = T; }
    __syncthreads();
    if (t == 0) {
        float ss = 0.0f, tt = 0.0f;
#pragma unroll
        for (int w = 0; w < 16; ++w) { ss += red[w]; tt += red[16 + w]; }
        const float oldS = atomicAdd(&accS[b], ss);
        const float oldT = atomicAdd(&accT[b], tt);
        asm volatile("" :: "v"(oldS), "v"(oldT));    // wait own atomics -> order ticket
        tickS = atomicAdd(ticket, 1u);
    }
    __syncthreads();
    if (tickS != 255u) return;             // uniform (LDS-shared)

    // ======================= final combine (last block) =======================
    if (t < BATCH) {
        sb[t] = atomicAdd(&accS[t], 0.0f); // coherent read-back
        tb[t] = atomicAdd(&accT[t], 0.0f);
    }
    __syncthreads();

    const int bb = t >> 8, bin = t & (NBINS - 1);
    const float invN = 1.0f / (float)NPIX;
    const float* __restrict__ q1 = S1part + ((size_t)bb << 14) + bin;  // 64 partials
    const float* __restrict__ q2 = S2part + ((size_t)bb << 14) + bin;
    float a1 = 0.0f, a2 = 0.0f;
#pragma unroll 8
    for (int j = 0; j < 64; ++j) { a1 += q1[(size_t)j << 8]; a2 += q2[(size_t)j << 8]; }
    const float pre1 = a1 * invN, pre2 = a2 * invN;

    auto segreduce = [&](float v) -> float {         // per-256 segment sum
        red[t] = v; __syncthreads();
        for (int st = 128; st > 0; st >>= 1) {
            if (bin < st) red[t] += red[t + st];
            __syncthreads();
        }
        const float r = red[bb << 8];
        __syncthreads();
        return r;
    };

    const float sum1 = segreduce(pre1);
    const float p1 = pre1 / (sum1 + EPSF);
    const float H1 = segreduce(-p1 * __log2f(p1 + EPSF));

    const float sum2 = segreduce(pre2);
    const float p2 = pre2 / (sum2 + EPSF);
    const float H2 = segreduce(-p2 * __log2f(p2 + EPSF));

    if (bin == 0) {
        const float Sp  = sb[bb] + EPSF;
        const float H12 = __log2f(Sp) * (sb[bb] / Sp) - tb[bb] / Sp;
        const float mi  = H1 + H2 - H12;
        nmiS[bb] = 2.0f * mi / (H1 + H2);
    }
    __syncthreads();
    if (t == 0) *out = 0.25f * (nmiS[0] + nmiS[1] + nmiS[2] + nmiS[3]);
}

// ---------------------------------------------------------------------------
extern "C" void kernel_launch(void* const* d_in, const int* in_sizes, int n_in,
                              void* d_out, int out_size, void* d_ws, size_t ws_size,
                              hipStream_t stream)
{
    const float* in1 = (const float*)d_in[0];
    const float* in2 = (const float*)d_in[1];

    float*    S1part = (float*)d_ws;                        // 4*64*256 = 64K
    float*    S2part = S1part + BATCH * NSTRIP * NQ * NBINS; // 64K
    float*    Jpart  = S2part + BATCH * NSTRIP * NQ * NBINS; // 4*4*65536 = 1M
    float*    accS   = Jpart + (size_t)BATCH * NQ * NBINS * NBINS;  // 4
    float*    accT   = accS + BATCH;                        // 4
    unsigned* ticket = (unsigned*)(accT + BATCH);           // 1
    float*    outp   = (float*)d_out;

    // All workspace fully overwritten / reset in-kernel each call ->
    // no memset nodes; exactly 2 kernel nodes.
    mi_strip<<<BATCH * NSTRIP * NQ, 1024, 0, stream>>>(
        in1, in2, S1part, S2part, Jpart, accS, accT, ticket);
    mi_entrop<<<256, 1024, 0, stream>>>(
        Jpart, S1part, S2part, accS, accT, ticket, outp);
}

// Round 11
// 30.032 us; speedup vs baseline: 3.2276x; 1.3734x over previous
//
#include <hip/hip_runtime.h>

#define NBINS    256
#define BATCH    4
#define NPIX     65536       // H*W per batch, C == 1
#define EPSF     1e-10f
#define RSTRIP   32          // joint rows owned per strip block
#define NSTRIP   8           // strips per batch
#define NSLICE   8           // pixel slices per batch
#define SLICEPIX (NPIX / NSLICE)   // 8192 pixels

// ---------------------------------------------------------------------------
// Node 1 (R9's verified strip): block (b,s,q) scans slice q of batch b into
// a 32 KB LDS strip (rows [32s,32s+32) of the joint histogram), flushed with
// plain coalesced stores to Jpart[blk]. 2-tap Gaussian (sigma=0.1, spacing
// 1.0 -> 3rd bin ~ exp(-50), < 1e-16 relative). Marginals: within slice q
// the wave-group (it*4 + t>>8) == s owns 1024 pixels (each pixel counted
// exactly once); partials plain-stored to M1part/M2part.
// No atomics, no resets, no memsets anywhere in the pipeline.
// ---------------------------------------------------------------------------
__global__ __launch_bounds__(1024) void mi_strip(
    const float* __restrict__ in1, const float* __restrict__ in2,
    float* __restrict__ Jpart, float* __restrict__ M1part,
    float* __restrict__ M2part)
{
    __shared__ float js[RSTRIP * NBINS];   // 32 KB
    __shared__ float h1[NBINS];
    __shared__ float h2[NBINS];

    const int t   = threadIdx.x;           // 0..1023
    const int blk = blockIdx.x;            // (b*8+s)*8+q
    const int b   = blk >> 6;
    const int s   = (blk >> 3) & (NSTRIP - 1);
    const int q   = blk & (NSLICE - 1);
    const int r0  = s << 5;

#pragma unroll
    for (int i = 0; i < 8; ++i) js[(i << 10) + t] = 0.0f;
    if (t < NBINS) { h1[t] = 0.0f; h2[t] = 0.0f; }
    __syncthreads();

    const float4* __restrict__ p1 = (const float4*)(in1 + b * NPIX) + q * (SLICEPIX / 4);
    const float4* __restrict__ p2 = (const float4*)(in2 + b * NPIX) + q * (SLICEPIX / 4);

#pragma unroll
    for (int it = 0; it < 2; ++it) {                 // 2048 float4 per slice
        const int l = (it << 10) + t;
        const float4 a = p1[l];
        const float4 c = p2[l];
        const bool mflag = ((it << 2) + (t >> 8)) == s;   // wave-uniform

        const float vx1[4] = { a.x, a.y, a.z, a.w };
        const float vx2[4] = { c.x, c.y, c.z, c.w };
#pragma unroll
        for (int j = 0; j < 4; ++j) {
            const float v1 = vx1[j] * 255.0f;        // in [0,255)
            const float v2 = vx2[j] * 255.0f;
            const int k1 = (int)v1;                  // floor, <= 254
            const int k2 = (int)v2;
            const float d1 = v1 - (float)k1;
            const float d2 = v2 - (float)k2;
            const float e1 = d1 - 1.0f;
            const float e2 = d2 - 1.0f;
            const float w1a = __expf(-50.0f * d1 * d1);
            const float w1b = __expf(-50.0f * e1 * e1);
            const float w2a = __expf(-50.0f * d2 * d2);
            const float w2b = __expf(-50.0f * e2 * e2);

            const int r = k1 - r0;
            if ((unsigned)r < RSTRIP) {              // row k1 in strip
                atomicAdd(&js[(r << 8) + k2],     w1a * w2a);
                atomicAdd(&js[(r << 8) + k2 + 1], w1a * w2b);
            }
            if ((unsigned)(r + 1) < RSTRIP) {        // row k1+1 in strip
                atomicAdd(&js[((r + 1) << 8) + k2],     w1b * w2a);
                atomicAdd(&js[((r + 1) << 8) + k2 + 1], w1b * w2b);
            }
            if (mflag) {
                atomicAdd(&h1[k1],     w1a);
                atomicAdd(&h1[k1 + 1], w1b);
                atomicAdd(&h2[k2],     w2a);
                atomicAdd(&h2[k2 + 1], w2b);
            }
        }
    }
    __syncthreads();

    float* __restrict__ Jq = Jpart + ((size_t)blk << 13);    // 8192 floats/blk
#pragma unroll
    for (int i = 0; i < 8; ++i) { const int idx = (i << 10) + t; Jq[idx] = js[idx]; }
    if (t < NBINS) {
        M1part[(blk << 8) + t] = h1[t];
        M2part[(blk << 8) + t] = h2[t];
    }
}

// ---------------------------------------------------------------------------
// Node 2: 256 blocks (full-device, unlike R6's 16). Block (b, rg) merges the
// 8 slice-partials for 4 joint rows (1 cell/thread, coalesced; 32 KB/block)
// and reduces S = sum(c), T = sum(c*log2 c) -- both LINEAR in c, so no
// normalization pass. Denormal guard (round-5 lesson): v_log_f32 flushes
// denormal input -> -inf -> NaN; guard at 1e-30 (|c log2 c| < 1e-28).
// Partial (S,T) plain-stored per block (NO last-block ticket: R9/R10 showed
// that pattern costs ~5.5 us vs a separate tiny node). Blocks with rg<8 also
// pre-merge the 8 slice marginal partials for strip rg -> M1m/M2m.
// ---------------------------------------------------------------------------
__global__ __launch_bounds__(1024) void mi_entrop(
    const float* __restrict__ Jpart,
    const float* __restrict__ M1part, const float* __restrict__ M2part,
    float* __restrict__ M1m, float* __restrict__ M2m,
    float* __restrict__ STs, float* __restrict__ STt)
{
    __shared__ float red[32];

    const int t   = threadIdx.x;
    const int g   = blockIdx.x;            // 0..255
    const int b   = g >> 6;
    const int rg  = g & 63;                // 4-row group within batch
    const int row = (rg << 2) + (t >> 8);  // 0..255
    const int col = t & (NBINS - 1);
    const int s   = row >> 5;              // strip holding this row
    const int lr  = row & (RSTRIP - 1);    // local row in strip

    const float* __restrict__ J0 = Jpart + ((size_t)(b * NSTRIP + s) << 16);
    const size_t off = ((size_t)lr << 8) + col;

    float c = 0.0f;
#pragma unroll
    for (int q = 0; q < NSLICE; ++q) c += J0[((size_t)q << 13) + off];
    float S = c;
    float T = (c > 1e-30f) ? c * __log2f(c) : 0.0f;
#pragma unroll
    for (int m = 32; m >= 1; m >>= 1) { S += __shfl_xor(S, m); T += __shfl_xor(T, m); }
    const int wid = t >> 6, lane = t & 63;
    if (lane == 0) { red[wid] = S; red[16 + wid] = T; }

    // marginal pre-merge: blocks rg<8, threads 0..511 (strip index = rg)
    if (rg < NSTRIP && t < 512) {
        const int arr = t >> 8, bin = t & (NBINS - 1);
        const float* __restrict__ Mp =
            (arr ? M2part : M1part) + ((size_t)((b * NSTRIP + rg) * NSLICE) << 8) + bin;
        float m = 0.0f;
#pragma unroll
        for (int q = 0; q < NSLICE; ++q) m += Mp[(size_t)q << 8];
        float* __restrict__ Mo = arr ? M2m : M1m;
        Mo[((b * NSTRIP + rg) << 8) + bin] = m;
    }
    __syncthreads();
    if (t == 0) {
        float ss = 0.0f, tt = 0.0f;
#pragma unroll
        for (int w = 0; w < 16; ++w) { ss += red[w]; tt += red[16 + w]; }
        STs[g] = ss; STt[g] = tt;
    }
}

// ---------------------------------------------------------------------------
// Node 3: one block. Reads 2 KB of (S,T) partials + 64 KB of pre-merged
// marginals. Reproduces the reference's eps placement for H1/H2; H12 via
// log2(S+eps)*S/(S+eps) - T/(S+eps) (~1e-5-bit deviation). Plain store.
// ---------------------------------------------------------------------------
__global__ __launch_bounds__(1024) void mi_combine(
    const float* __restrict__ M1m, const float* __restrict__ M2m,
    const float* __restrict__ STs, const float* __restrict__ STt,
    float* __restrict__ out)
{
    __shared__ float red[1024];
    __shared__ float sb[BATCH], tb[BATCH], nmiS[BATCH];

    const int t = threadIdx.x;
    const int wid = t >> 6, lane = t & 63;
    if (wid < BATCH) {                     // 64 (S,T) partials per batch
        float Sv = STs[(wid << 6) + lane];
        float Tv = STt[(wid << 6) + lane];
#pragma unroll
        for (int m = 32; m >= 1; m >>= 1) { Sv += __shfl_xor(Sv, m); Tv += __shfl_xor(Tv, m); }
        if (lane == 0) { sb[wid] = Sv; tb[wid] = Tv; }
    }
    __syncthreads();

    const int bb = t >> 8, bin = t & (NBINS - 1);
    const float invN = 1.0f / (float)NPIX;
    float a1 = 0.0f, a2 = 0.0f;
#pragma unroll
    for (int s = 0; s < NSTRIP; ++s) {
        const int idx = ((bb * NSTRIP + s) << 8) + bin;
        a1 += M1m[idx];
        a2 += M2m[idx];
    }
    const float pre1 = a1 * invN, pre2 = a2 * invN;

    auto segreduce = [&](float v) -> float {         // per-256 segment sum
        red[t] = v; __syncthreads();
        for (int st = 128; st > 0; st >>= 1) {
            if (bin < st) red[t] += red[t + st];
            __syncthreads();
        }
        const float r = red[bb << 8];
        __syncthreads();
        return r;
    };

    const float sum1 = segreduce(pre1);
    const float p1 = pre1 / (sum1 + EPSF);
    const float H1 = segreduce(-p1 * __log2f(p1 + EPSF));

    const float sum2 = segreduce(pre2);
    const float p2 = pre2 / (sum2 + EPSF);
    const float H2 = segreduce(-p2 * __log2f(p2 + EPSF));

    if (bin == 0) {
        const float Sp  = sb[bb] + EPSF;
        const float H12 = __log2f(Sp) * (sb[bb] / Sp) - tb[bb] / Sp;
        const float mi  = H1 + H2 - H12;
        nmiS[bb] = 2.0f * mi / (H1 + H2);
    }
    __syncthreads();
    if (t == 0) *out = 0.25f * (nmiS[0] + nmiS[1] + nmiS[2] + nmiS[3]);
}

// ---------------------------------------------------------------------------
extern "C" void kernel_launch(void* const* d_in, const int* in_sizes, int n_in,
                              void* d_out, int out_size, void* d_ws, size_t ws_size,
                              hipStream_t stream)
{
    const float* in1 = (const float*)d_in[0];
    const float* in2 = (const float*)d_in[1];

    float* Jpart  = (float*)d_ws;                     // 256*8192 = 2M floats (8 MB)
    float* M1part = Jpart + (size_t)256 * 8192;       // 256*256
    float* M2part = M1part + 65536;                   // 256*256
    float* M1m    = M2part + 65536;                   // 32*256
    float* M2m    = M1m + 8192;                       // 32*256
    float* STs    = M2m + 8192;                       // 256
    float* STt    = STs + 256;                        // 256
    float* outp   = (float*)d_out;

    // Every workspace word is overwritten before it is read each call ->
    // no memsets, no atomics, no tickets; 3 kernel nodes, plain-store handoffs.
    mi_strip<<<BATCH * NSTRIP * NSLICE, 1024, 0, stream>>>(in1, in2, Jpart, M1part, M2part);
    mi_entrop<<<256, 1024, 0, stream>>>(Jpart, M1part, M2part, M1m, M2m, STs, STt);
    mi_combine<<<1, 1024, 0, stream>>>(M1m, M2m, STs, STt, outp);
}

// Round 12
// 28.989 us; speedup vs baseline: 3.3438x; 1.0360x over previous
//
#include <hip/hip_runtime.h>

#define NBINS    256
#define BATCH    4
#define NPIX     65536       // H*W per batch, C == 1
#define EPSF     1e-10f
#define RSTRIP   32          // joint rows owned per strip block
#define NSTRIP   8           // strips per batch
#define NSLICE   8           // pixel slices per batch
#define SLICEPIX (NPIX / NSLICE)   // 8192 pixels

// ---------------------------------------------------------------------------
// Node 1: block (b,s,q) scans slice q of batch b into a 32 KB LDS strip
// (rows [32s,32s+32) of the joint histogram), flushed with plain coalesced
// float4 stores to Jpart[blk]. 2-tap Gaussian (sigma=0.1, spacing 1.0 ->
// 3rd bin ~ exp(-50), < 1e-16 relative). Marginals: within slice q the
// wave-group (it*4 + t>>8) == s owns 1024 pixels (each pixel counted exactly
// once); partials plain-stored. No atomics/resets/memsets in the pipeline.
// ---------------------------------------------------------------------------
__global__ __launch_bounds__(1024) void mi_strip(
    const float* __restrict__ in1, const float* __restrict__ in2,
    float* __restrict__ Jpart, float* __restrict__ M1part,
    float* __restrict__ M2part)
{
    __shared__ float js[RSTRIP * NBINS];   // 32 KB
    __shared__ float h1[NBINS];
    __shared__ float h2[NBINS];

    const int t   = threadIdx.x;           // 0..1023
    const int blk = blockIdx.x;            // (b*8+s)*8+q
    const int b   = blk >> 6;
    const int s   = (blk >> 3) & (NSTRIP - 1);
    const int q   = blk & (NSLICE - 1);
    const int r0  = s << 5;

    // vectorized zero: thread owns js[8t..8t+7] (2x ds_write_b128)
    {
        const float4 z = { 0.0f, 0.0f, 0.0f, 0.0f };
        float4* __restrict__ js4 = (float4*)js;
        js4[(t << 1)]     = z;
        js4[(t << 1) + 1] = z;
    }
    if (t < NBINS) { h1[t] = 0.0f; h2[t] = 0.0f; }
    __syncthreads();

    const float4* __restrict__ p1 = (const float4*)(in1 + b * NPIX) + q * (SLICEPIX / 4);
    const float4* __restrict__ p2 = (const float4*)(in2 + b * NPIX) + q * (SLICEPIX / 4);

#pragma unroll
    for (int it = 0; it < 2; ++it) {                 // 2048 float4 per slice
        const int l = (it << 10) + t;
        const float4 a = p1[l];
        const float4 c = p2[l];
        const bool mflag = ((it << 2) + (t >> 8)) == s;   // wave-uniform

        const float vx1[4] = { a.x, a.y, a.z, a.w };
        const float vx2[4] = { c.x, c.y, c.z, c.w };
#pragma unroll
        for (int j = 0; j < 4; ++j) {
            const float v1 = vx1[j] * 255.0f;        // in [0,255)
            const float v2 = vx2[j] * 255.0f;
            const int k1 = (int)v1;                  // floor, <= 254
            const int k2 = (int)v2;
            const float d1 = v1 - (float)k1;
            const float d2 = v2 - (float)k2;
            const float e1 = d1 - 1.0f;
            const float e2 = d2 - 1.0f;
            const float w1a = __expf(-50.0f * d1 * d1);
            const float w1b = __expf(-50.0f * e1 * e1);
            const float w2a = __expf(-50.0f * d2 * d2);
            const float w2b = __expf(-50.0f * e2 * e2);

            const int r = k1 - r0;
            if ((unsigned)r < RSTRIP) {              // row k1 in strip
                atomicAdd(&js[(r << 8) + k2],     w1a * w2a);
                atomicAdd(&js[(r << 8) + k2 + 1], w1a * w2b);
            }
            if ((unsigned)(r + 1) < RSTRIP) {        // row k1+1 in strip
                atomicAdd(&js[((r + 1) << 8) + k2],     w1b * w2a);
                atomicAdd(&js[((r + 1) << 8) + k2 + 1], w1b * w2b);
            }
            if (mflag) {
                atomicAdd(&h1[k1],     w1a);
                atomicAdd(&h1[k1 + 1], w1b);
                atomicAdd(&h2[k2],     w2a);
                atomicAdd(&h2[k2 + 1], w2b);
            }
        }
    }
    __syncthreads();

    // vectorized flush (identity index map: entrop's view unchanged)
    {
        const float4* __restrict__ js4 = (const float4*)js;
        float4* __restrict__ Jq4 = (float4*)(Jpart + ((size_t)blk << 13));
        Jq4[(t << 1)]     = js4[(t << 1)];
        Jq4[(t << 1) + 1] = js4[(t << 1) + 1];
    }
    if (t < NBINS) {
        M1part[(blk << 8) + t] = h1[t];
        M2part[(blk << 8) + t] = h2[t];
    }
}

// ---------------------------------------------------------------------------
// Node 2: 256 blocks (full device). Block (b, rg) merges the 8 slice
// partials for 4 joint rows (1 cell/thread, coalesced) and reduces
// S = sum(c), T = sum(c*log2 c) -- both LINEAR in c, so no normalization
// pass. Denormal guard (round-5 lesson): v_log_f32 flushes denormal input
// -> -inf -> NaN; guard at 1e-30 (|c log2 c| < 1e-28). (S,T) plain-stored
// per block (no ticket: R9/R10 showed it loses to a separate tiny node).
// Blocks rg<8 also pre-merge the 8 slice marginal partials for strip rg.
// ---------------------------------------------------------------------------
__global__ __launch_bounds__(1024) void mi_entrop(
    const float* __restrict__ Jpart,
    const float* __restrict__ M1part, const float* __restrict__ M2part,
    float* __restrict__ M1m, float* __restrict__ M2m,
    float* __restrict__ STs, float* __restrict__ STt)
{
    __shared__ float red[32];

    const int t   = threadIdx.x;
    const int g   = blockIdx.x;            // 0..255
    const int b   = g >> 6;
    const int rg  = g & 63;                // 4-row group within batch
    const int row = (rg << 2) + (t >> 8);  // 0..255
    const int col = t & (NBINS - 1);
    const int s   = row >> 5;              // strip holding this row
    const int lr  = row & (RSTRIP - 1);    // local row in strip

    const float* __restrict__ J0 = Jpart + ((size_t)(b * NSTRIP + s) << 16);
    const size_t off = ((size_t)lr << 8) + col;

    float c = 0.0f;
#pragma unroll
    for (int q = 0; q < NSLICE; ++q) c += J0[((size_t)q << 13) + off];
    float S = c;
    float T = (c > 1e-30f) ? c * __log2f(c) : 0.0f;
#pragma unroll
    for (int m = 32; m >= 1; m >>= 1) { S += __shfl_xor(S, m); T += __shfl_xor(T, m); }
    const int wid = t >> 6, lane = t & 63;
    if (lane == 0) { red[wid] = S; red[16 + wid] = T; }

    // marginal pre-merge: blocks rg<8, threads 0..511 (strip index = rg)
    if (rg < NSTRIP && t < 512) {
        const int arr = t >> 8, bin = t & (NBINS - 1);
        const float* __restrict__ Mp =
            (arr ? M2part : M1part) + ((size_t)((b * NSTRIP + rg) * NSLICE) << 8) + bin;
        float m = 0.0f;
#pragma unroll
        for (int q = 0; q < NSLICE; ++q) m += Mp[(size_t)q << 8];
        float* __restrict__ Mo = arr ? M2m : M1m;
        Mo[((b * NSTRIP + rg) << 8) + bin] = m;
    }
    __syncthreads();
    if (t == 0) {
        float ss = 0.0f, tt = 0.0f;
#pragma unroll
        for (int w = 0; w < 16; ++w) { ss += red[w]; tt += red[16 + w]; }
        STs[g] = ss; STt[g] = tt;
    }
}

// ---------------------------------------------------------------------------
// Node 3: one block. Barrier-lean: each segreduce = wave shfl_xor reduce
// (no barrier) -> 16 wave partials to a DISTINCT red slot -> ONE barrier ->
// per-thread sum of its segment's 4 partials. 4 barriers total (was 32).
// Reproduces the reference's eps placement for H1/H2; H12 via
// log2(S+eps)*S/(S+eps) - T/(S+eps) (~1e-5-bit deviation). Plain store.
// ---------------------------------------------------------------------------
__global__ __launch_bounds__(1024) void mi_combine(
    const float* __restrict__ M1m, const float* __restrict__ M2m,
    const float* __restrict__ STs, const float* __restrict__ STt,
    float* __restrict__ out)
{
    __shared__ float red[64];
    __shared__ float sb[BATCH], tb[BATCH], nmiS[BATCH];

    const int t = threadIdx.x;
    const int wid = t >> 6, lane = t & 63;
    const int bb = t >> 8, bin = t & (NBINS - 1);

    // joint (S,T): wave wid<4 merges batch wid's 64 partials (no barrier;
    // consumed after the segreduce barriers below)
    if (wid < BATCH) {
        float Sv = STs[(wid << 6) + lane];
        float Tv = STt[(wid << 6) + lane];
#pragma unroll
        for (int m = 32; m >= 1; m >>= 1) { Sv += __shfl_xor(Sv, m); Tv += __shfl_xor(Tv, m); }
        if (lane == 0) { sb[wid] = Sv; tb[wid] = Tv; }
    }

    // marginal merge: 8 pre-merged partials per (batch, bin)
    const float invN = 1.0f / (float)NPIX;
    float a1 = 0.0f, a2 = 0.0f;
#pragma unroll
    for (int s = 0; s < NSTRIP; ++s) {
        const int idx = ((bb * NSTRIP + s) << 8) + bin;
        a1 += M1m[idx];
        a2 += M2m[idx];
    }
    const float pre1 = a1 * invN, pre2 = a2 * invN;

    // segreduce: per-256-thread segment sum, one barrier, distinct slot base
    auto segreduce = [&](float v, int base) -> float {
#pragma unroll
        for (int m = 32; m >= 1; m >>= 1) v += __shfl_xor(v, m);
        if (lane == 0) red[base + wid] = v;
        __syncthreads();
        const int sb4 = base + (bb << 2);
        return red[sb4] + red[sb4 + 1] + red[sb4 + 2] + red[sb4 + 3];
    };

    const float sum1 = segreduce(pre1, 0);
    const float p1 = pre1 / (sum1 + EPSF);
    const float H1 = segreduce(-p1 * __log2f(p1 + EPSF), 16);

    const float sum2 = segreduce(pre2, 32);
    const float p2 = pre2 / (sum2 + EPSF);
    const float H2 = segreduce(-p2 * __log2f(p2 + EPSF), 48);

    if (bin == 0) {
        const float Sp  = sb[bb] + EPSF;
        const float H12 = __log2f(Sp) * (sb[bb] / Sp) - tb[bb] / Sp;
        const float mi  = H1 + H2 - H12;
        nmiS[bb] = 2.0f * mi / (H1 + H2);
    }
    __syncthreads();
    if (t == 0) *out = 0.25f * (nmiS[0] + nmiS[1] + nmiS[2] + nmiS[3]);
}

// ---------------------------------------------------------------------------
extern "C" void kernel_launch(void* const* d_in, const int* in_sizes, int n_in,
                              void* d_out, int out_size, void* d_ws, size_t ws_size,
                              hipStream_t stream)
{
    const float* in1 = (const float*)d_in[0];
    const float* in2 = (const float*)d_in[1];

    float* Jpart  = (float*)d_ws;                     // 256*8192 floats (8 MB)
    float* M1part = Jpart + (size_t)256 * 8192;       // 256*256
    float* M2part = M1part + 65536;                   // 256*256
    float* M1m    = M2part + 65536;                   // 32*256
    float* M2m    = M1m + 8192;                       // 32*256
    float* STs    = M2m + 8192;                       // 256
    float* STt    = STs + 256;                        // 256
    float* outp   = (float*)d_out;

    // Every workspace word is overwritten before it is read each call ->
    // no memsets, no atomics, no tickets; 3 kernel nodes, plain-store handoffs.
    mi_strip<<<BATCH * NSTRIP * NSLICE, 1024, 0, stream>>>(in1, in2, Jpart, M1part, M2part);
    mi_entrop<<<256, 1024, 0, stream>>>(Jpart, M1part, M2part, M1m, M2m, STs, STt);
    mi_combine<<<1, 1024, 0, stream>>>(M1m, M2m, STs, STt, outp);
}